// Round 2
// baseline (1598.687 us; speedup 1.0000x reference)
//
#include <hip/hip_runtime.h>

// ---------------------------------------------------------------------------
// StructureModule (IPA), B=1 L=1024 C=384 H=12 P=128, SQK=SV=16, PQK=4, PV=8
// Round 1: dtype-agnostic. A detector kernel decides (at device runtime)
// whether float inputs are stored f32 or bf16; all small inputs are converted
// to f32 workspace copies; only the inputs_2d hot-loop load and the final
// store keep dual paths. Output dtype follows input dtype.
// ---------------------------------------------------------------------------

#define LL 1024
#define CC 384
#define HH 12
#define PP 128

static constexpr float SCALAR_W = 0.14433756729740643f;   // sqrt(1/48)
static constexpr float POINT_WC = 0.1360827634879543f;    // sqrt(1/54)
static constexpr float PAIR_W   = 0.5773502691896258f;    // sqrt(1/3)
static constexpr float LOG2E    = 1.4426950408889634f;

// ---- ws layout (float offsets) ----
#define OFF_IN1D   16
#define OFF_ROT    393232
#define OFF_TRANS  402448
#define OFF_WQ     405520
#define OFF_BQ     479248
#define OFF_WKV    479440
#define OFF_BKV    626896
#define OFF_WQP    627280
#define OFF_BQP    682576
#define OFF_WKVP   682720
#define OFF_BKVP   848608
#define OFF_WPAIR  849040
#define OFF_BPAIR  850576
#define OFF_TPW    850588
#define OFF_WOUT   850600
#define OFF_BOUT   1661608
#define OFF_PROJ   1662000
#define OFF_QPACK  2841648
#define OFF_KPACK  3234864
#define OFF_FIN    4119600
// end: 6,282,288 floats = 25.1 MB

__device__ __forceinline__ float fromlo(unsigned int v) {
    unsigned int a = v << 16; float f; __builtin_memcpy(&f, &a, 4); return f;
}
__device__ __forceinline__ float fromhi(unsigned int v) {
    unsigned int a = v & 0xffff0000u; float f; __builtin_memcpy(&f, &a, 4); return f;
}
__device__ __forceinline__ unsigned short f2bf(float f) {
    unsigned int u; __builtin_memcpy(&u, &f, 4);
    unsigned int lsb = (u >> 16) & 1u;
    u += 0x7fffu + lsb;
    return (unsigned short)(u >> 16);
}
__device__ __forceinline__ float red16(float v) {
    v += __shfl_xor(v, 1);
    v += __shfl_xor(v, 2);
    v += __shfl_xor(v, 4);
    v += __shfl_xor(v, 8);
    return v;
}

// ------------------------- K0: dtype detector ------------------------------
// If in1d is really f32, even ushort indices are f32 mantissa words -> bf16
// interpretation has uniform exponent bits -> some |x| >= 2^33 among 256
// samples with overwhelming probability. Genuine N(0,1) bf16 never does.
__global__ __launch_bounds__(256) void k_detect(const unsigned short* __restrict__ in1d,
                                                int* __restrict__ flag) {
    __shared__ int f;
    if (threadIdx.x == 0) f = 0;
    __syncthreads();
    unsigned short u = in1d[threadIdx.x * 2];
    if ((u & 0x7FFF) >= 0x5000) atomicOr(&f, 1);
    __syncthreads();
    if (threadIdx.x == 0) flag[0] = f;   // 1 => inputs are f32
}

// ------------------- K0b: convert all small inputs to f32 ------------------
struct CvtArgs { const void* src[16]; int n[16]; int off[16]; };

__global__ __launch_bounds__(256) void k_cvt(CvtArgs a, float* __restrict__ ws) {
    int which = blockIdx.y;
    int n = a.n[which];
    int i4 = (blockIdx.x * 256 + threadIdx.x) * 4;
    if (i4 >= n) return;
    bool f32 = ((const int*)ws)[0] != 0;
    float4 o;
    if (f32) {
        o = *(const float4*)((const float*)a.src[which] + i4);
    } else {
        uint2 u = *(const uint2*)((const unsigned short*)a.src[which] + i4);
        o.x = fromlo(u.x); o.y = fromhi(u.x); o.z = fromlo(u.y); o.w = fromhi(u.y);
    }
    *(float4*)(ws + a.off[which] + i4) = o;
}

// --------------------------- K1: projection GEMM ---------------------------
__global__ __launch_bounds__(256) void k_proj(const float* __restrict__ A,
                                              const float* __restrict__ W,
                                              const float* __restrict__ bias,
                                              float* __restrict__ proj,
                                              int N, int colOff) {
    __shared__ float lA[4][CC];
    int t = threadIdx.x;
    int row0 = blockIdx.x * 4;
    for (int e = 0; e < 6; ++e) {
        int idx = e * 256 + t;              // 1536 = 4*384
        int r = idx / CC, k = idx - r * CC;
        lA[r][k] = A[(size_t)(row0 + r) * CC + k];
    }
    __syncthreads();
    int r = t >> 6;
    int c = (t & 63) + blockIdx.y * 64;
    if (c < N) {
        float acc = bias[c];
        const float* wc = W + c;
#pragma unroll 8
        for (int k = 0; k < CC; ++k) acc = fmaf(lA[r][k], wc[(size_t)k * N], acc);
        proj[(size_t)(row0 + r) * 1152 + colOff + c] = acc;
    }
}

// ------------------- K1b: rigid transforms + pack Q/K/V --------------------
__global__ __launch_bounds__(192) void k_pack(const float* __restrict__ proj,
                                              const float* __restrict__ rot,
                                              const float* __restrict__ trans,
                                              const float* __restrict__ tpw,
                                              const float* __restrict__ bpair,
                                              float* __restrict__ Qpack,
                                              float* __restrict__ Kpack) {
    int l = blockIdx.x;
    int t = threadIdx.x;
    int h = t >> 4, lane = t & 15;
    const float* pr = proj + (size_t)l * 1152;

    float R[3][3], tv[3];
#pragma unroll
    for (int x = 0; x < 3; ++x) {
#pragma unroll
        for (int y = 0; y < 3; ++y) R[x][y] = rot[(size_t)l * 9 + x * 3 + y];
        tv[x] = trans[(size_t)l * 3 + x];
    }
    float sp = log1pf(expf(tpw[h]));               // softplus
    float pw = -0.5f * POINT_WC * sp;

    size_t qb = ((size_t)l * HH + h) * 32;
    size_t kb = ((size_t)l * HH + h) * 72;

    Qpack[qb + lane] = LOG2E * SCALAR_W * pr[h * 16 + lane];
    Kpack[kb + lane]      = pr[192 + h * 32 + lane];
    Kpack[kb + 16 + lane] = pr[192 + h * 32 + 16 + lane];

    float tq = 0.f, sqq_p = 0.f;
    if (lane < 12) {
        int p = lane / 3, x = lane - p * 3;
        int n = h * 4 + p;
        float r0 = pr[576 + n], r1 = pr[576 + 48 + n], r2 = pr[576 + 96 + n];
        tq = fmaf(R[x][0], r0, fmaf(R[x][1], r1, fmaf(R[x][2], r2, tv[x])));
        sqq_p = tq * tq;
    }
    float sqq = red16(sqq_p);
    if (lane < 12) Qpack[qb + 16 + lane] = LOG2E * (-2.f * pw) * tq;
    if (lane == 0) Qpack[qb + 28] = LOG2E * (pw * sqq + PAIR_W * bpair[h]);

    float sqk_p = 0.f;
#pragma unroll
    for (int e = 0; e < 3; ++e) {
        int m = e * 16 + lane;
        if (m < 36) {
            int jj = m / 3, x = m - jj * 3;
            int mp = h * 12 + jj;
            float p0 = pr[720 + mp], p1 = pr[720 + 144 + mp], p2 = pr[720 + 288 + mp];
            float tk = fmaf(R[x][0], p0, fmaf(R[x][1], p1, fmaf(R[x][2], p2, tv[x])));
            if (jj < 4) { Kpack[kb + 32 + jj * 3 + x] = tk; sqk_p += tk * tk; }
            else        { Kpack[kb + 44 + (jj - 4) * 3 + x] = tk; }
        }
    }
    float sqk = red16(sqk_p);
    if (lane == 0) Kpack[kb + 68] = LOG2E * pw * sqk;
}

// ----------------------- K2: fused attention (1 block / i) -----------------
__global__ __launch_bounds__(192) void k_attn(const void* __restrict__ in2d,
                                              const float* __restrict__ rot,
                                              const float* __restrict__ trans,
                                              const float* __restrict__ Wpairf,
                                              const float* __restrict__ Qpack,
                                              const float* __restrict__ Kpack,
                                              const int* __restrict__ flagp,
                                              float* __restrict__ fin) {
    int i = blockIdx.x;
    int t = threadIdx.x;
    int h = t >> 4, lane = t & 15;
    bool f32m = (*flagp != 0);

    size_t qb = ((size_t)i * HH + h) * 32;
    float qv  = Qpack[qb + lane];
    float qpv = (lane < 12) ? Qpack[qb + 16 + lane] : 0.f;
    float cb  = Qpack[qb + 28];
    float wp[8];
#pragma unroll
    for (int k = 0; k < 8; ++k)
        wp[k] = LOG2E * PAIR_W * Wpairf[(size_t)(lane * 8 + k) * HH + h];

    float S = 0.f, avs = 0.f, aA = 0.f, aB = 0.f;
    float r2[8] = {0.f, 0.f, 0.f, 0.f, 0.f, 0.f, 0.f, 0.f};

    const unsigned short* p2b = (const unsigned short*)in2d + (size_t)i * LL * PP + lane * 8;
    const float*          p2f = (const float*)in2d          + (size_t)i * LL * PP + lane * 8;

#pragma unroll 2
    for (int j = 0; j < LL; ++j) {
        const float* kbp = Kpack + ((size_t)j * HH + h) * 72;
        float kv    = kbp[lane];
        float vv    = kbp[16 + lane];
        float kpv   = (lane < 12) ? kbp[32 + lane] : 0.f;
        float extra = (lane == 13) ? kbp[68] : 0.f;
        float vA    = kbp[44 + lane];
        float vB    = (lane < 8) ? kbp[60 + lane] : 0.f;

        float x0, x1, x2, x3, x4, x5, x6, x7;
        if (f32m) {
            float4 a = *(const float4*)(p2f + (size_t)j * PP);
            float4 b = *(const float4*)(p2f + (size_t)j * PP + 4);
            x0 = a.x; x1 = a.y; x2 = a.z; x3 = a.w;
            x4 = b.x; x5 = b.y; x6 = b.z; x7 = b.w;
        } else {
            uint4 u = *(const uint4*)(p2b + (size_t)j * PP);
            x0 = fromlo(u.x); x1 = fromhi(u.x);
            x2 = fromlo(u.y); x3 = fromhi(u.y);
            x4 = fromlo(u.z); x5 = fromhi(u.z);
            x6 = fromlo(u.w); x7 = fromhi(u.w);
        }

        float part = fmaf(qv, kv, fmaf(qpv, kpv, extra));
        part = fmaf(wp[0], x0, part); part = fmaf(wp[1], x1, part);
        part = fmaf(wp[2], x2, part); part = fmaf(wp[3], x3, part);
        part = fmaf(wp[4], x4, part); part = fmaf(wp[5], x5, part);
        part = fmaf(wp[6], x6, part); part = fmaf(wp[7], x7, part);
        part = red16(part);

        float w = exp2f(part + cb);
        S += w;
        avs = fmaf(w, vv, avs);
        aA  = fmaf(w, vA, aA);
        aB  = fmaf(w, vB, aB);
        r2[0] = fmaf(w, x0, r2[0]); r2[1] = fmaf(w, x1, r2[1]);
        r2[2] = fmaf(w, x2, r2[2]); r2[3] = fmaf(w, x3, r2[3]);
        r2[4] = fmaf(w, x4, r2[4]); r2[5] = fmaf(w, x5, r2[5]);
        r2[6] = fmaf(w, x6, r2[6]); r2[7] = fmaf(w, x7, r2[7]);
    }

    float inv = 1.0f / S;
    float* fb = fin + (size_t)i * 2112;

    fb[h * 16 + lane] = avs * inv;    // r_s

    __shared__ float lrp[HH * 24];
    lrp[h * 24 + lane] = aA * inv;
    if (lane < 8) lrp[h * 24 + 16 + lane] = aB * inv;
    __syncthreads();
    if (lane < 8) {
        float R[3][3], tv[3];
#pragma unroll
        for (int x = 0; x < 3; ++x) {
#pragma unroll
            for (int y = 0; y < 3; ++y) R[x][y] = rot[(size_t)i * 9 + x * 3 + y];
            tv[x] = trans[(size_t)i * 3 + x];
        }
        int m = lane;
        float ry0 = lrp[h * 24 + m * 3 + 0] - tv[0];
        float ry1 = lrp[h * 24 + m * 3 + 1] - tv[1];
        float ry2 = lrp[h * 24 + m * 3 + 2] - tv[2];
        float l0 = fmaf(R[0][0], ry0, fmaf(R[1][0], ry1, R[2][0] * ry2));
        float l1 = fmaf(R[0][1], ry0, fmaf(R[1][1], ry1, R[2][1] * ry2));
        float l2 = fmaf(R[0][2], ry0, fmaf(R[1][2], ry1, R[2][2] * ry2));
        fb[192 +       h * 8 + m] = l0;
        fb[192 +  96 + h * 8 + m] = l1;
        fb[192 + 192 + h * 8 + m] = l2;
        fb[480 + h * 8 + m] = sqrtf(fmaf(l0, l0, fmaf(l1, l1, fmaf(l2, l2, 1e-8f))));
    }

    float4 ra = {r2[0] * inv, r2[1] * inv, r2[2] * inv, r2[3] * inv};
    float4 rb = {r2[4] * inv, r2[5] * inv, r2[6] * inv, r2[7] * inv};
    *(float4*)(fb + 576 + h * PP + lane * 8)     = ra;
    *(float4*)(fb + 576 + h * PP + lane * 8 + 4) = rb;
}

// -------------------- K4: out = final @ Wout + bout ------------------------
__global__ __launch_bounds__(384) void k_out(const float* __restrict__ fin,
                                             const float* __restrict__ Wf,
                                             const float* __restrict__ boutf,
                                             void* __restrict__ out,
                                             const int* __restrict__ flagp) {
    __shared__ float lA[4 * 2112];
    int t = threadIdx.x;
    int l0 = blockIdx.x * 4;
    for (int e = 0; e < 22; ++e) {
        int idx = e * 384 + t;                 // 8448 = 384*22
        int r = idx / 2112, k = idx - r * 2112;
        lA[idx] = fin[(size_t)(l0 + r) * 2112 + k];
    }
    __syncthreads();
    int r = t / 96, g = t - r * 96;
    int c0 = g * 4;
    const float* lrow = lA + r * 2112;
    float a0 = 0.f, a1 = 0.f, a2 = 0.f, a3 = 0.f;
#pragma unroll 4
    for (int k = 0; k < 2112; ++k) {
        float a = lrow[k];
        float4 w = *(const float4*)(Wf + (size_t)k * CC + c0);
        a0 = fmaf(a, w.x, a0); a1 = fmaf(a, w.y, a1);
        a2 = fmaf(a, w.z, a2); a3 = fmaf(a, w.w, a3);
    }
    a0 += boutf[c0]; a1 += boutf[c0 + 1]; a2 += boutf[c0 + 2]; a3 += boutf[c0 + 3];
    size_t base = (size_t)(l0 + r) * CC + c0;
    if (*flagp != 0) {
        float4 o = {a0, a1, a2, a3};
        *(float4*)((float*)out + base) = o;
    } else {
        ushort4 o = {f2bf(a0), f2bf(a1), f2bf(a2), f2bf(a3)};
        *(ushort4*)((unsigned short*)out + base) = o;
    }
}

// ---------------------------------------------------------------------------
extern "C" void kernel_launch(void* const* d_in, const int* in_sizes, int n_in,
                              void* d_out, int out_size, void* d_ws, size_t ws_size,
                              hipStream_t stream) {
    float* ws = (float*)d_ws;
    int* flag = (int*)d_ws;

    k_detect<<<1, 256, 0, stream>>>((const unsigned short*)d_in[0], flag);

    CvtArgs a;
    const int srcIdx[16] = {0, 2, 3, 5, 7, 9, 11, 13, 6, 8, 10, 12, 14, 15, 16, 17};
    const int ns[16]     = {393216, 9216, 3072, 73728, 147456, 55296, 165888, 1536,
                            192, 384, 144, 432, 12, 12, 811008, 384};
    const int offs[16]   = {OFF_IN1D, OFF_ROT, OFF_TRANS, OFF_WQ, OFF_WKV, OFF_WQP,
                            OFF_WKVP, OFF_WPAIR, OFF_BQ, OFF_BKV, OFF_BQP, OFF_BKVP,
                            OFF_BPAIR, OFF_TPW, OFF_WOUT, OFF_BOUT};
    for (int i = 0; i < 16; ++i) { a.src[i] = d_in[srcIdx[i]]; a.n[i] = ns[i]; a.off[i] = offs[i]; }
    k_cvt<<<dim3(792, 16), 256, 0, stream>>>(a, ws);

    float* in1d  = ws + OFF_IN1D;
    float* proj  = ws + OFF_PROJ;
    k_proj<<<dim3(256, 3), 256, 0, stream>>>(in1d, ws + OFF_WQ,   ws + OFF_BQ,   proj, 192, 0);
    k_proj<<<dim3(256, 6), 256, 0, stream>>>(in1d, ws + OFF_WKV,  ws + OFF_BKV,  proj, 384, 192);
    k_proj<<<dim3(256, 3), 256, 0, stream>>>(in1d, ws + OFF_WQP,  ws + OFF_BQP,  proj, 144, 576);
    k_proj<<<dim3(256, 7), 256, 0, stream>>>(in1d, ws + OFF_WKVP, ws + OFF_BKVP, proj, 432, 720);
    k_pack<<<1024, 192, 0, stream>>>(proj, ws + OFF_ROT, ws + OFF_TRANS,
                                     ws + OFF_TPW, ws + OFF_BPAIR,
                                     ws + OFF_QPACK, ws + OFF_KPACK);
    k_attn<<<1024, 192, 0, stream>>>(d_in[1], ws + OFF_ROT, ws + OFF_TRANS,
                                     ws + OFF_WPAIR, ws + OFF_QPACK, ws + OFF_KPACK,
                                     flag, ws + OFF_FIN);
    k_out<<<256, 384, 0, stream>>>(ws + OFF_FIN, ws + OFF_WOUT, ws + OFF_BOUT,
                                   d_out, flag);
}

// Round 3
// 1408.492 us; speedup vs baseline: 1.1350x; 1.1350x over previous
//
#include <hip/hip_runtime.h>

// ---------------------------------------------------------------------------
// StructureModule (IPA), B=1 L=1024 C=384 H=12 P=128, SQK=SV=16, PQK=4, PV=8
// Round 2: k_attn occupancy fix. Profile showed Occupancy 35% (3 waves/block,
// 4 blocks/CU = 12/32 waves) and VALUBusy 26% -> latency-bound. New k_attn:
// 960 threads = 15 waves = 5 j-chunks x (12 heads x 16 lanes); per-chunk
// partial (S, sum w*v) accumulators combined exactly via LDS (no-max softmax
// is associative). 2 blocks/CU x 15 waves = 30/32 waves = 94% occupancy.
// inputs confirmed bf16 from FETCH_SIZE (277MB ~= bf16 inputs_2d).
// ---------------------------------------------------------------------------

#define LL 1024
#define CC 384
#define HH 12
#define PP 128
#define NCH 5
#define CHJ 205

static constexpr float SCALAR_W = 0.14433756729740643f;   // sqrt(1/48)
static constexpr float POINT_WC = 0.1360827634879543f;    // sqrt(1/54)
static constexpr float PAIR_W   = 0.5773502691896258f;    // sqrt(1/3)
static constexpr float LOG2E    = 1.4426950408889634f;

// ---- ws layout (float offsets) ----
#define OFF_IN1D   16
#define OFF_ROT    393232
#define OFF_TRANS  402448
#define OFF_WQ     405520
#define OFF_BQ     479248
#define OFF_WKV    479440
#define OFF_BKV    626896
#define OFF_WQP    627280
#define OFF_BQP    682576
#define OFF_WKVP   682720
#define OFF_BKVP   848608
#define OFF_WPAIR  849040
#define OFF_BPAIR  850576
#define OFF_TPW    850588
#define OFF_WOUT   850600
#define OFF_BOUT   1661608
#define OFF_PROJ   1662000
#define OFF_QPACK  2841648
#define OFF_KPACK  3234864
#define OFF_FIN    4119600
// end: 6,282,288 floats = 25.1 MB

__device__ __forceinline__ float fromlo(unsigned int v) {
    unsigned int a = v << 16; float f; __builtin_memcpy(&f, &a, 4); return f;
}
__device__ __forceinline__ float fromhi(unsigned int v) {
    unsigned int a = v & 0xffff0000u; float f; __builtin_memcpy(&f, &a, 4); return f;
}
__device__ __forceinline__ unsigned short f2bf(float f) {
    unsigned int u; __builtin_memcpy(&u, &f, 4);
    unsigned int lsb = (u >> 16) & 1u;
    u += 0x7fffu + lsb;
    return (unsigned short)(u >> 16);
}
__device__ __forceinline__ float red16(float v) {
    v += __shfl_xor(v, 1);
    v += __shfl_xor(v, 2);
    v += __shfl_xor(v, 4);
    v += __shfl_xor(v, 8);
    return v;
}

// ------------------------- K0: dtype detector ------------------------------
__global__ __launch_bounds__(256) void k_detect(const unsigned short* __restrict__ in1d,
                                                int* __restrict__ flag) {
    __shared__ int f;
    if (threadIdx.x == 0) f = 0;
    __syncthreads();
    unsigned short u = in1d[threadIdx.x * 2];
    if ((u & 0x7FFF) >= 0x5000) atomicOr(&f, 1);
    __syncthreads();
    if (threadIdx.x == 0) flag[0] = f;   // 1 => inputs are f32
}

// ------------------- K0b: convert all small inputs to f32 ------------------
struct CvtArgs { const void* src[16]; int n[16]; int off[16]; };

__global__ __launch_bounds__(256) void k_cvt(CvtArgs a, float* __restrict__ ws) {
    int which = blockIdx.y;
    int n = a.n[which];
    int i4 = (blockIdx.x * 256 + threadIdx.x) * 4;
    if (i4 >= n) return;
    bool f32 = ((const int*)ws)[0] != 0;
    float4 o;
    if (f32) {
        o = *(const float4*)((const float*)a.src[which] + i4);
    } else {
        uint2 u = *(const uint2*)((const unsigned short*)a.src[which] + i4);
        o.x = fromlo(u.x); o.y = fromhi(u.x); o.z = fromlo(u.y); o.w = fromhi(u.y);
    }
    *(float4*)(ws + a.off[which] + i4) = o;
}

// --------------------------- K1: projection GEMM ---------------------------
__global__ __launch_bounds__(256) void k_proj(const float* __restrict__ A,
                                              const float* __restrict__ W,
                                              const float* __restrict__ bias,
                                              float* __restrict__ proj,
                                              int N, int colOff) {
    __shared__ float lA[4][CC];
    int t = threadIdx.x;
    int row0 = blockIdx.x * 4;
    for (int e = 0; e < 6; ++e) {
        int idx = e * 256 + t;              // 1536 = 4*384
        int r = idx / CC, k = idx - r * CC;
        lA[r][k] = A[(size_t)(row0 + r) * CC + k];
    }
    __syncthreads();
    int r = t >> 6;
    int c = (t & 63) + blockIdx.y * 64;
    if (c < N) {
        float acc = bias[c];
        const float* wc = W + c;
#pragma unroll 8
        for (int k = 0; k < CC; ++k) acc = fmaf(lA[r][k], wc[(size_t)k * N], acc);
        proj[(size_t)(row0 + r) * 1152 + colOff + c] = acc;
    }
}

// ------------------- K1b: rigid transforms + pack Q/K/V --------------------
__global__ __launch_bounds__(192) void k_pack(const float* __restrict__ proj,
                                              const float* __restrict__ rot,
                                              const float* __restrict__ trans,
                                              const float* __restrict__ tpw,
                                              const float* __restrict__ bpair,
                                              float* __restrict__ Qpack,
                                              float* __restrict__ Kpack) {
    int l = blockIdx.x;
    int t = threadIdx.x;
    int h = t >> 4, lane = t & 15;
    const float* pr = proj + (size_t)l * 1152;

    float R[3][3], tv[3];
#pragma unroll
    for (int x = 0; x < 3; ++x) {
#pragma unroll
        for (int y = 0; y < 3; ++y) R[x][y] = rot[(size_t)l * 9 + x * 3 + y];
        tv[x] = trans[(size_t)l * 3 + x];
    }
    float sp = log1pf(expf(tpw[h]));               // softplus
    float pw = -0.5f * POINT_WC * sp;

    size_t qb = ((size_t)l * HH + h) * 32;
    size_t kb = ((size_t)l * HH + h) * 72;

    Qpack[qb + lane] = LOG2E * SCALAR_W * pr[h * 16 + lane];
    Kpack[kb + lane]      = pr[192 + h * 32 + lane];
    Kpack[kb + 16 + lane] = pr[192 + h * 32 + 16 + lane];

    float tq = 0.f, sqq_p = 0.f;
    if (lane < 12) {
        int p = lane / 3, x = lane - p * 3;
        int n = h * 4 + p;
        float r0 = pr[576 + n], r1 = pr[576 + 48 + n], r2 = pr[576 + 96 + n];
        tq = fmaf(R[x][0], r0, fmaf(R[x][1], r1, fmaf(R[x][2], r2, tv[x])));
        sqq_p = tq * tq;
    }
    float sqq = red16(sqq_p);
    if (lane < 12) Qpack[qb + 16 + lane] = LOG2E * (-2.f * pw) * tq;
    if (lane == 0) Qpack[qb + 28] = LOG2E * (pw * sqq + PAIR_W * bpair[h]);

    float sqk_p = 0.f;
#pragma unroll
    for (int e = 0; e < 3; ++e) {
        int m = e * 16 + lane;
        if (m < 36) {
            int jj = m / 3, x = m - jj * 3;
            int mp = h * 12 + jj;
            float p0 = pr[720 + mp], p1 = pr[720 + 144 + mp], p2 = pr[720 + 288 + mp];
            float tk = fmaf(R[x][0], p0, fmaf(R[x][1], p1, fmaf(R[x][2], p2, tv[x])));
            if (jj < 4) { Kpack[kb + 32 + jj * 3 + x] = tk; sqk_p += tk * tk; }
            else        { Kpack[kb + 44 + (jj - 4) * 3 + x] = tk; }
        }
    }
    float sqk = red16(sqk_p);
    if (lane == 0) Kpack[kb + 68] = LOG2E * pw * sqk;
}

// ------------- K2: fused attention, 5 j-chunks in-block (960 thr) ----------
__global__ __launch_bounds__(960) void k_attn(const void* __restrict__ in2d,
                                              const float* __restrict__ rot,
                                              const float* __restrict__ trans,
                                              const float* __restrict__ Wpairf,
                                              const float* __restrict__ Qpack,
                                              const float* __restrict__ Kpack,
                                              const int* __restrict__ flagp,
                                              float* __restrict__ fin) {
    int i = blockIdx.x;
    int t = threadIdx.x;                 // 0..959
    int c = t / 192;                     // j-chunk 0..4 (wave-aligned: 192=3 waves)
    int w = t - c * 192;
    int h = w >> 4, lane = w & 15;
    bool f32m = (*flagp != 0);

    size_t qb = ((size_t)i * HH + h) * 32;
    float qv  = Qpack[qb + lane];
    float qpv = (lane < 12) ? Qpack[qb + 16 + lane] : 0.f;
    float cb  = Qpack[qb + 28];
    float laneC = (lane == 14) ? cb : 0.f;   // fold cb into lane14's logit part
    float wp[8];
#pragma unroll
    for (int k = 0; k < 8; ++k)
        wp[k] = LOG2E * PAIR_W * Wpairf[(size_t)(lane * 8 + k) * HH + h];

    float S = 0.f, avs = 0.f, aA = 0.f, aB = 0.f;
    float r2[8] = {0.f, 0.f, 0.f, 0.f, 0.f, 0.f, 0.f, 0.f};

    const unsigned short* p2b = (const unsigned short*)in2d + (size_t)i * LL * PP + lane * 8;
    const float*          p2f = (const float*)in2d          + (size_t)i * LL * PP + lane * 8;

    int j0 = c * CHJ;
    int j1 = j0 + CHJ; if (j1 > LL) j1 = LL;

#pragma unroll 2
    for (int j = j0; j < j1; ++j) {
        const float* kbp = Kpack + ((size_t)j * HH + h) * 72;
        float kv    = kbp[lane];
        float vv    = kbp[16 + lane];
        float kpv   = (lane < 12) ? kbp[32 + lane] : 0.f;
        float extra = (lane == 13) ? kbp[68] : laneC;
        float vA    = kbp[44 + lane];
        float vB    = (lane < 8) ? kbp[60 + lane] : 0.f;

        float x0, x1, x2, x3, x4, x5, x6, x7;
        if (f32m) {
            float4 a = *(const float4*)(p2f + (size_t)j * PP);
            float4 b = *(const float4*)(p2f + (size_t)j * PP + 4);
            x0 = a.x; x1 = a.y; x2 = a.z; x3 = a.w;
            x4 = b.x; x5 = b.y; x6 = b.z; x7 = b.w;
        } else {
            uint4 u = *(const uint4*)(p2b + (size_t)j * PP);
            x0 = fromlo(u.x); x1 = fromhi(u.x);
            x2 = fromlo(u.y); x3 = fromhi(u.y);
            x4 = fromlo(u.z); x5 = fromhi(u.z);
            x6 = fromlo(u.w); x7 = fromhi(u.w);
        }

        float part = fmaf(qv, kv, fmaf(qpv, kpv, extra));
        part = fmaf(wp[0], x0, part); part = fmaf(wp[1], x1, part);
        part = fmaf(wp[2], x2, part); part = fmaf(wp[3], x3, part);
        part = fmaf(wp[4], x4, part); part = fmaf(wp[5], x5, part);
        part = fmaf(wp[6], x6, part); part = fmaf(wp[7], x7, part);
        part = red16(part);

        float wgt = exp2f(part);
        S += wgt;
        avs = fmaf(wgt, vv, avs);
        aA  = fmaf(wgt, vA, aA);
        aB  = fmaf(wgt, vB, aB);
        r2[0] = fmaf(wgt, x0, r2[0]); r2[1] = fmaf(wgt, x1, r2[1]);
        r2[2] = fmaf(wgt, x2, r2[2]); r2[3] = fmaf(wgt, x3, r2[3]);
        r2[4] = fmaf(wgt, x4, r2[4]); r2[5] = fmaf(wgt, x5, r2[5]);
        r2[6] = fmaf(wgt, x6, r2[6]); r2[7] = fmaf(wgt, x7, r2[7]);
    }

    // ---- LDS combine of 5 chunk-partials (exact: pure sum reorder) ----
    __shared__ float ldsA[NCH][HH][44];   // avs16 | aA16 | aB8 | S@40
    __shared__ float ldsR[NCH][HH][PP];
    ldsA[c][h][lane] = avs;
    ldsA[c][h][16 + lane] = aA;
    if (lane < 8) ldsA[c][h][32 + lane] = aB;
    if (lane == 0) ldsA[c][h][40] = S;
#pragma unroll
    for (int e = 0; e < 8; ++e) ldsR[c][h][lane * 8 + e] = r2[e];
    __syncthreads();
    if (c != 0) return;

    float Sv = 0.f, A = 0.f, Pv = 0.f, Bv = 0.f;
    float rr[8] = {0.f, 0.f, 0.f, 0.f, 0.f, 0.f, 0.f, 0.f};
#pragma unroll
    for (int cc = 0; cc < NCH; ++cc) {
        Sv += ldsA[cc][h][40];
        A  += ldsA[cc][h][lane];
        Pv += ldsA[cc][h][16 + lane];
        Bv += ldsA[cc][h][32 + (lane & 7)];
#pragma unroll
        for (int e = 0; e < 8; ++e) rr[e] += ldsR[cc][h][lane * 8 + e];
    }
    float inv = 1.0f / Sv;
    float* fb = fin + (size_t)i * 2112;

    fb[h * 16 + lane] = A * inv;    // r_s

    __shared__ float lrp[HH * 24];
    lrp[h * 24 + lane] = Pv * inv;
    if (lane < 8) lrp[h * 24 + 16 + lane] = Bv * inv;
    // lrp traffic for head h stays within one wave (192=3 waves, 4 h/wave):
    // no barrier needed, compiler inserts lgkmcnt.
    if (lane < 8) {
        float R[3][3], tv[3];
#pragma unroll
        for (int x = 0; x < 3; ++x) {
#pragma unroll
            for (int y = 0; y < 3; ++y) R[x][y] = rot[(size_t)i * 9 + x * 3 + y];
            tv[x] = trans[(size_t)i * 3 + x];
        }
        int m = lane;
        float ry0 = lrp[h * 24 + m * 3 + 0] - tv[0];
        float ry1 = lrp[h * 24 + m * 3 + 1] - tv[1];
        float ry2 = lrp[h * 24 + m * 3 + 2] - tv[2];
        float l0 = fmaf(R[0][0], ry0, fmaf(R[1][0], ry1, R[2][0] * ry2));
        float l1 = fmaf(R[0][1], ry0, fmaf(R[1][1], ry1, R[2][1] * ry2));
        float l2 = fmaf(R[0][2], ry0, fmaf(R[1][2], ry1, R[2][2] * ry2));
        fb[192 +       h * 8 + m] = l0;
        fb[192 +  96 + h * 8 + m] = l1;
        fb[192 + 192 + h * 8 + m] = l2;
        fb[480 + h * 8 + m] = sqrtf(fmaf(l0, l0, fmaf(l1, l1, fmaf(l2, l2, 1e-8f))));
    }

    float4 ra = {rr[0] * inv, rr[1] * inv, rr[2] * inv, rr[3] * inv};
    float4 rb = {rr[4] * inv, rr[5] * inv, rr[6] * inv, rr[7] * inv};
    *(float4*)(fb + 576 + h * PP + lane * 8)     = ra;
    *(float4*)(fb + 576 + h * PP + lane * 8 + 4) = rb;
}

// -------------------- K4: out = final @ Wout + bout ------------------------
__global__ __launch_bounds__(384) void k_out(const float* __restrict__ fin,
                                             const float* __restrict__ Wf,
                                             const float* __restrict__ boutf,
                                             void* __restrict__ out,
                                             const int* __restrict__ flagp) {
    __shared__ float lA[4 * 2112];
    int t = threadIdx.x;
    int l0 = blockIdx.x * 4;
    for (int e = 0; e < 22; ++e) {
        int idx = e * 384 + t;                 // 8448 = 384*22
        int r = idx / 2112, k = idx - r * 2112;
        lA[idx] = fin[(size_t)(l0 + r) * 2112 + k];
    }
    __syncthreads();
    int r = t / 96, g = t - r * 96;
    int c0 = g * 4;
    const float* lrow = lA + r * 2112;
    float a0 = 0.f, a1 = 0.f, a2 = 0.f, a3 = 0.f;
#pragma unroll 4
    for (int k = 0; k < 2112; ++k) {
        float a = lrow[k];
        float4 w = *(const float4*)(Wf + (size_t)k * CC + c0);
        a0 = fmaf(a, w.x, a0); a1 = fmaf(a, w.y, a1);
        a2 = fmaf(a, w.z, a2); a3 = fmaf(a, w.w, a3);
    }
    a0 += boutf[c0]; a1 += boutf[c0 + 1]; a2 += boutf[c0 + 2]; a3 += boutf[c0 + 3];
    size_t base = (size_t)(l0 + r) * CC + c0;
    if (*flagp != 0) {
        float4 o = {a0, a1, a2, a3};
        *(float4*)((float*)out + base) = o;
    } else {
        ushort4 o = {f2bf(a0), f2bf(a1), f2bf(a2), f2bf(a3)};
        *(ushort4*)((unsigned short*)out + base) = o;
    }
}

// ---------------------------------------------------------------------------
extern "C" void kernel_launch(void* const* d_in, const int* in_sizes, int n_in,
                              void* d_out, int out_size, void* d_ws, size_t ws_size,
                              hipStream_t stream) {
    float* ws = (float*)d_ws;
    int* flag = (int*)d_ws;

    k_detect<<<1, 256, 0, stream>>>((const unsigned short*)d_in[0], flag);

    CvtArgs a;
    const int srcIdx[16] = {0, 2, 3, 5, 7, 9, 11, 13, 6, 8, 10, 12, 14, 15, 16, 17};
    const int ns[16]     = {393216, 9216, 3072, 73728, 147456, 55296, 165888, 1536,
                            192, 384, 144, 432, 12, 12, 811008, 384};
    const int offs[16]   = {OFF_IN1D, OFF_ROT, OFF_TRANS, OFF_WQ, OFF_WKV, OFF_WQP,
                            OFF_WKVP, OFF_WPAIR, OFF_BQ, OFF_BKV, OFF_BQP, OFF_BKVP,
                            OFF_BPAIR, OFF_TPW, OFF_WOUT, OFF_BOUT};
    for (int i = 0; i < 16; ++i) { a.src[i] = d_in[srcIdx[i]]; a.n[i] = ns[i]; a.off[i] = offs[i]; }
    k_cvt<<<dim3(792, 16), 256, 0, stream>>>(a, ws);

    float* in1d  = ws + OFF_IN1D;
    float* proj  = ws + OFF_PROJ;
    k_proj<<<dim3(256, 3), 256, 0, stream>>>(in1d, ws + OFF_WQ,   ws + OFF_BQ,   proj, 192, 0);
    k_proj<<<dim3(256, 6), 256, 0, stream>>>(in1d, ws + OFF_WKV,  ws + OFF_BKV,  proj, 384, 192);
    k_proj<<<dim3(256, 3), 256, 0, stream>>>(in1d, ws + OFF_WQP,  ws + OFF_BQP,  proj, 144, 576);
    k_proj<<<dim3(256, 7), 256, 0, stream>>>(in1d, ws + OFF_WKVP, ws + OFF_BKVP, proj, 432, 720);
    k_pack<<<1024, 192, 0, stream>>>(proj, ws + OFF_ROT, ws + OFF_TRANS,
                                     ws + OFF_TPW, ws + OFF_BPAIR,
                                     ws + OFF_QPACK, ws + OFF_KPACK);
    k_attn<<<1024, 960, 0, stream>>>(d_in[1], ws + OFF_ROT, ws + OFF_TRANS,
                                     ws + OFF_WPAIR, ws + OFF_QPACK, ws + OFF_KPACK,
                                     flag, ws + OFF_FIN);
    k_out<<<256, 384, 0, stream>>>(ws + OFF_FIN, ws + OFF_WOUT, ws + OFF_BOUT,
                                   d_out, flag);
}